// Round 4
// baseline (540.294 us; speedup 1.0000x reference)
//
#include <hip/hip_runtime.h>
#include <stdint.h>

#define NUM_CLASSES 80u
#define TOPK 1000
#define CONF_T 0.05f
#define NMS_T 0.6f
#define MAX_COORD 4096.0f
#define TARGET 1152u            // top-1000 + tie/superset slack
#define CAP 49152u              // candidate buffer capacity
#define SRVCAP 2048u            // survivor buffer (>= TARGET + boundary ties)
#define NBINS 4096              // coarse bins = key >> 20 (12 bits)
#define STATIC_KEY 0xC0800000u  // fkey(+4.0f): static candidate prefilter
#define STATIC_BIN 3080u        // STATIC_KEY >> 20

typedef unsigned long long ull;
typedef ull ull2 __attribute__((ext_vector_type(2)));

// Monotone float->uint key: descending float == descending key
__device__ __forceinline__ uint32_t fkey(float x) {
  uint32_t k = __float_as_uint(x);
  return (k & 0x80000000u) ? ~k : (k | 0x80000000u);
}

// ---------------- kernel Z: zero hist + counters (ws poisoned 0xAA) -------
__global__ void kz(uint32_t* histC, uint32_t* sel) {
  int t = threadIdx.x;
  for (int i = t; i < NBINS; i += 1024) histC[i] = 0u;
  if (t < 16) sel[t] = 0u;
}

// ---------------- kernel A: positive histogram + static compact -----------
// Histograms x >= +0 (bins >= 2048); simultaneously compacts x >= +4.0
// candidates (~28K for this data) so no second full scan is needed.
__global__ void __launch_bounds__(256) kA(const float4* __restrict__ cls, int n4,
                                          uint32_t* histC, uint32_t* sel,
                                          uint32_t* candKey, uint32_t* candIdx) {
  __shared__ uint32_t h[NBINS * 2];
  for (int i = threadIdx.x; i < NBINS * 2; i += 256) h[i] = 0u;
  __syncthreads();
  uint32_t sub = threadIdx.x & 1u;
  int stride = gridDim.x * blockDim.x;
  for (int i = blockIdx.x * blockDim.x + threadIdx.x; i < n4; i += stride) {
    float4 v = cls[i];
    uint32_t k4[4] = {fkey(v.x), fkey(v.y), fkey(v.z), fkey(v.w)};
#pragma unroll
    for (int c = 0; c < 4; ++c) {
      uint32_t k = k4[c];
      if (k & 0x80000000u) atomicAdd(&h[((k >> 20) << 1) | sub], 1u);
      if (k >= STATIC_KEY) {
        uint32_t pos = atomicAdd(&sel[2], 1u);  // wave-aggregated by compiler
        if (pos < CAP) { candKey[pos] = k; candIdx[pos] = (uint32_t)i * 4u + c; }
      }
    }
  }
  __syncthreads();
  for (int i = threadIdx.x; i < NBINS; i += 256) {
    uint32_t c = h[i * 2] + h[i * 2 + 1];
    if (c) atomicAdd(&histC[i], c);
  }
}

// ---------------- kernel B: parallel suffix-scan bin pick -----------------
// sel[0]=bin, sel[1]=count above bin, sel[3]=needRescan (bin < STATIC_BIN).
__global__ void __launch_bounds__(1024) kB(const uint32_t* __restrict__ histC,
                                           uint32_t* sel) {
  __shared__ uint32_t s[1024];
  int t = threadIdx.x;
  uint32_t c0 = histC[t * 4 + 0], c1 = histC[t * 4 + 1];
  uint32_t c2 = histC[t * 4 + 2], c3 = histC[t * 4 + 3];
  s[t] = c0 + c1 + c2 + c3;
  __syncthreads();
  for (int off = 1; off < 1024; off <<= 1) {
    uint32_t add = (t + off < 1024) ? s[t + off] : 0u;
    __syncthreads();
    s[t] += add;
    __syncthreads();
  }
  uint32_t suff = s[t];
  uint32_t above = (t < 1023) ? s[t + 1] : 0u;
  bool crossing = (suff >= TARGET) && (t == 1023 || above < TARGET);
  if (crossing) {
    uint32_t cum = above;
    uint32_t cc[4] = {c0, c1, c2, c3};
    for (int j = 3; j >= 0; --j) {
      if (cum + cc[j] >= TARGET) {
        uint32_t bin = (uint32_t)(t * 4 + j);
        sel[0] = bin; sel[1] = cum;
        sel[3] = (bin < STATIC_BIN) ? 1u : 0u;
        break;
      }
      cum += cc[j];
    }
  }
  if (t == 512 && suff < TARGET) {  // degenerate: positives < TARGET
    sel[0] = 2048u; sel[1] = suff - c0; sel[3] = 1u;
  }
}

// ---------------- kernel E: fallback rescan (early-exit normally) ---------
// Only runs the scan when the threshold bin fell below the static prefilter;
// appends the missing range {bsel <= bin, key < STATIC_KEY} to cand.
__global__ void kE(const float4* __restrict__ cls, int n4,
                   uint32_t* sel, uint32_t* candKey, uint32_t* candIdx) {
  if (sel[3] == 0u) return;  // static prefilter covered the threshold
  uint32_t bsel = sel[0];
  int stride = gridDim.x * blockDim.x;
  for (int i = blockIdx.x * blockDim.x + threadIdx.x; i < n4; i += stride) {
    float4 v = cls[i];
    uint32_t k4[4] = {fkey(v.x), fkey(v.y), fkey(v.z), fkey(v.w)};
#pragma unroll
    for (int c = 0; c < 4; ++c) {
      uint32_t k = k4[c];
      if ((k >> 20) >= bsel && k < STATIC_KEY) {
        uint32_t pos = atomicAdd(&sel[2], 1u);
        if (pos < CAP) { candKey[pos] = k; candIdx[pos] = (uint32_t)i * 4u + c; }
      }
    }
  }
}

// ---------------- kernel F1: refine threshold + select survivors ----------
// Single block: fine histogram -> exact-enough threshold T; survivors
// (key >= T, ~1200) written to global srv as (p_bits<<32 | ~idx).
// Also prefills outputs for degenerate (scount < 1000) safety.
__global__ void __launch_bounds__(1024) kF1(
    const float* __restrict__ cls, const uint32_t* __restrict__ sel_ro,
    uint32_t* sel, const uint32_t* __restrict__ candKey,
    const uint32_t* __restrict__ candIdx,
    ull* __restrict__ srv, float* __restrict__ out, float* __restrict__ topScore) {
  __shared__ uint32_t fh[1024];
  __shared__ uint32_t TkeyS;
  int tid = threadIdx.x;
  uint32_t n = sel_ro[2]; if (n > CAP) n = CAP;
  uint32_t bsel = sel_ro[0], above = sel_ro[1];

  for (int i = tid; i < 1024; i += 1024) fh[i] = 0u;
  __syncthreads();
  for (uint32_t i = tid; i < n; i += 1024u) {
    uint32_t k = candKey[i];
    if ((k >> 20) == bsel) atomicAdd(&fh[(k >> 10) & 1023u], 1u);
  }
  __syncthreads();
  if (tid == 0) {
    uint32_t cum = above; int s = 1023;
    for (; s >= 0; --s) { cum += fh[s]; if (cum >= TARGET) break; }
    if (s < 0) s = 0;
    TkeyS = (bsel << 20) | ((uint32_t)s << 10);
  }
  __syncthreads();
  uint32_t T = TkeyS;

  for (uint32_t i = tid; i < n; i += 1024u) {
    uint32_t k = candKey[i];
    if (k >= T) {
      uint32_t pos = atomicAdd(&sel[4], 1u);
      if (pos < SRVCAP) {
        uint32_t idx = candIdx[i];
        float x = cls[idx];
        float p = 1.0f / (1.0f + expf(-x));  // np fp32 sigmoid
        srv[pos] = ((ull)__float_as_uint(p) << 32) | (ull)(uint32_t)(~idx);
      }
    }
  }
  // prefill (covers degenerate scount < 1000; cheap)
  for (int i = tid; i < 4000; i += 1024) out[i] = 0.0f;
  for (int i = tid; i < 1000; i += 1024) { out[5000 + i] = 0.0f; topScore[i] = 0.0f; }
}

// ---------------- kernel F2: rank survivors + emit ------------------------
// 32 blocks x 64: stage all survivor keys into LDS; thread i computes
// rank_i = #{j: skey_j > skey_i} (exact, keys unique) and emits row rank_i.
__global__ void __launch_bounds__(64) kF2(
    const float* __restrict__ box, const int* __restrict__ ph,
    const int* __restrict__ pw, const uint32_t* __restrict__ sel,
    const ull* __restrict__ srv, float* __restrict__ out,
    float* __restrict__ topScore, float* __restrict__ obox) {
  __shared__ __align__(16) ull sk[SRVCAP];
  int t = threadIdx.x;
  uint32_t scount = sel[4]; if (scount > SRVCAP) scount = SRVCAP;
  uint32_t pad = (scount + 1u) & ~1u;
  for (uint32_t i = t; i < pad; i += 64u) sk[i] = (i < scount) ? srv[i] : 0ull;
  __syncthreads();
  uint32_t i = blockIdx.x * 64u + (uint32_t)t;
  if (i >= scount) return;
  ull my = sk[i];
  uint32_t rank = 0;
#pragma unroll 4
  for (uint32_t j = 0; j < pad; j += 2u) {
    ull2 v = *reinterpret_cast<const ull2*>(&sk[j]);  // b128 broadcast read
    rank += (v.x > my) + (v.y > my);
  }
  if (rank >= TOPK) return;
  uint32_t idx = ~(uint32_t)my;
  float p = __uint_as_float((uint32_t)(my >> 32));
  uint32_t label = idx % NUM_CLASSES;
  uint32_t anchor = idx / NUM_CLASSES;
  float W = (float)pw[0], H = (float)ph[0];
  float b0 = box[anchor * 4u + 0u], b1 = box[anchor * 4u + 1u];
  float b2 = box[anchor * 4u + 2u], b3 = box[anchor * 4u + 3u];
  out[rank * 4 + 0] = fminf(fmaxf(b0 / W, 0.0f), 1.0f);
  out[rank * 4 + 1] = fminf(fmaxf(b1 / H, 0.0f), 1.0f);
  out[rank * 4 + 2] = fminf(fmaxf(b2 / W, 0.0f), 1.0f);
  out[rank * 4 + 3] = fminf(fmaxf(b3 / H, 0.0f), 1.0f);
  out[5000 + rank] = (float)label;
  topScore[rank] = p;
  float off = (float)label * MAX_COORD;  // class-aware NMS offset
  obox[rank * 4 + 0] = b0 + off; obox[rank * 4 + 1] = b1 + off;
  obox[rank * 4 + 2] = b2 + off; obox[rank * 4 + 3] = b3 + off;
}

// ---------------- kernel G: IoU suppression bitmasks (j > i) --------------
__global__ void kG(const float* __restrict__ obox, ull* __restrict__ masks) {
  int i = blockIdx.x;  // row 0..999
  float x1i = obox[i * 4 + 0], y1i = obox[i * 4 + 1];
  float x2i = obox[i * 4 + 2], y2i = obox[i * 4 + 3];
  float ai = (x2i - x1i) * (y2i - y1i);
  for (int base = 0; base < 1024; base += 256) {
    int jj = base + (int)threadIdx.x;
    bool bit = false;
    if (jj < TOPK && jj > i) {
      float x1j = obox[jj * 4 + 0], y1j = obox[jj * 4 + 1];
      float x2j = obox[jj * 4 + 2], y2j = obox[jj * 4 + 3];
      float aj = (x2j - x1j) * (y2j - y1j);
      float ix1 = fmaxf(x1i, x1j), iy1 = fmaxf(y1i, y1j);
      float ix2 = fminf(x2i, x2j), iy2 = fminf(y2i, y2j);
      float iw = fmaxf(ix2 - ix1, 0.0f), ih = fmaxf(iy2 - iy1, 0.0f);
      float inter = iw * ih;
      float iou = inter / (ai + aj - inter + 1e-9f);
      bit = iou > NMS_T;
    }
    ull m = __ballot(bit);
    if ((threadIdx.x & 63u) == 0u) masks[i * 16 + (jj >> 6)] = m;
  }
}

// ---------------- kernel H: LDS-staged single-wave greedy NMS -------------
__global__ void __launch_bounds__(256) kH(const float* __restrict__ topScore,
                                          const ull* __restrict__ masks,
                                          float* __restrict__ out) {
  __shared__ ull lmask[TOPK * 16];
  __shared__ uint32_t nzrow[TOPK];
  __shared__ ull keepsh[16];
  int t = threadIdx.x;
  for (int i = t; i < TOPK; i += 256) nzrow[i] = 0u;
  if (t < 16) keepsh[t] = 0ull;
  __syncthreads();
  for (int i = t; i < TOPK * 16; i += 256) {
    ull m = masks[i];
    lmask[i] = m;
    if (m) atomicOr(&nzrow[i >> 4], 1u);
  }
  for (int base = 0; base < 1024; base += 256) {
    int r = base + t;
    bool v = (r < TOPK) && (topScore[r] > CONF_T);
    ull b = __ballot(v);
    if ((t & 63) == 0) keepsh[(base >> 6) + (t >> 6)] = b;
  }
  __syncthreads();
  if (t < 64) {  // single-wave greedy loop, no barriers inside
    ull kw = (t < 16) ? keepsh[t] : 0ull;
    ull nzw = 0ull;
    if (t < 16) {
      for (int b = 0; b < 64; ++b) {
        int r = t * 64 + b;
        if (r < TOPK && nzrow[r]) nzw |= 1ull << b;
      }
    }
    for (int w = 0; w < 16; ++w) {
      ull cur = __shfl(kw, w) & __shfl(nzw, w);
      while (cur) {
        int b = __ffsll((long long)cur) - 1;
        int i = w * 64 + b;
        if (t < 16) kw &= ~lmask[i * 16 + t];  // row i suppresses only j > i
        ull nk = __shfl(kw, w);
        cur = nk & __shfl(nzw, w);
        cur &= (b == 63) ? 0ull : (~0ull << (b + 1));
      }
    }
    if (t < 16) keepsh[t] = kw;
  }
  __syncthreads();
  for (int r = t; r < TOPK; r += 256) {
    bool k = (keepsh[r >> 6] >> (r & 63)) & 1ull;
    float s = topScore[r];
    out[4000 + r] = k ? s : 0.0f;
    out[6000 + r] = k ? 1.0f : 0.0f;
  }
}

extern "C" void kernel_launch(void* const* d_in, const int* in_sizes, int n_in,
                              void* d_out, int out_size, void* d_ws, size_t ws_size,
                              hipStream_t stream) {
  const float* cls = (const float*)d_in[0];  // (1, N, 80) logits
  const float* box = (const float*)d_in[1];  // (1, N, 4)
  const int* ph = (const int*)d_in[2];       // img_h
  const int* pw = (const int*)d_in[3];       // img_w
  float* out = (float*)d_out;                // [boxes 4000 | scores 1000 | labels 1000 | keep 1000]
  int n = in_sizes[0];                       // 20,971,520 (divisible by 4)

  uint8_t* w = (uint8_t*)d_ws;
  uint32_t* histC   = (uint32_t*)(w);                               // 16 KB
  uint32_t* sel     = (uint32_t*)(w + 16384);                       // 64 B
  uint32_t* candKey = (uint32_t*)(w + 20480);                       // 192 KB
  uint32_t* candIdx = (uint32_t*)(w + 20480 + (size_t)CAP * 4);     // 192 KB
  ull*      srv     = (ull*)     (w + 20480 + (size_t)CAP * 8);     // 16 KB
  float*    topScore= (float*)   (w + 20480 + (size_t)CAP * 8 + 16384);         // 4 KB
  float*    obox    = (float*)   (w + 20480 + (size_t)CAP * 8 + 16384 + 4096);  // 16 KB
  ull*      masks   = (ull*)     (w + 20480 + (size_t)CAP * 8 + 16384 + 4096 + 16384); // 128 KB

  kz <<<1, 1024, 0, stream>>>(histC, sel);
  kA <<<2048, 256, 0, stream>>>((const float4*)cls, n / 4, histC, sel, candKey, candIdx);
  kB <<<1, 1024, 0, stream>>>(histC, sel);
  kE <<<2048, 256, 0, stream>>>((const float4*)cls, n / 4, sel, candKey, candIdx);
  kF1<<<1, 1024, 0, stream>>>(cls, sel, sel, candKey, candIdx, srv, out, topScore);
  kF2<<<SRVCAP / 64, 64, 0, stream>>>(box, ph, pw, sel, srv, out, topScore, obox);
  kG <<<TOPK, 256, 0, stream>>>(obox, masks);
  kH <<<1, 256, 0, stream>>>(topScore, masks, out);
}

// Round 5
// 277.215 us; speedup vs baseline: 1.9490x; 1.9490x over previous
//
#include <hip/hip_runtime.h>
#include <stdint.h>

#define NUM_CLASSES 80u
#define TOPK 1000
#define CONF_T 0.05f
#define NMS_T 0.6f
#define MAX_COORD 4096.0f
#define TARGET 1152u            // top-1000 + tie/superset slack
#define CAP 49152u              // candidate buffer capacity
#define SRVCAP 2048u            // survivor buffer (>= TARGET + boundary ties)
#define NBINS 4096              // coarse bins = key >> 20 (12 bits)
#define STATIC_KEY 0xC0800000u  // fkey(+4.0f): static candidate prefilter
#define STATIC_BIN 3080u        // STATIC_KEY >> 20
#define LCAP 512u               // per-block LDS candidate staging

typedef unsigned long long ull;
typedef ull ull2 __attribute__((ext_vector_type(2)));

// Monotone float->uint key: descending float == descending key
__device__ __forceinline__ uint32_t fkey(float x) {
  uint32_t k = __float_as_uint(x);
  return (k & 0x80000000u) ? ~k : (k | 0x80000000u);
}

// ---------------- kernel Z: zero hist + counters (ws poisoned 0xAA) -------
__global__ void kz(uint32_t* histC, uint32_t* sel) {
  int t = threadIdx.x;
  for (int i = t; i < NBINS; i += 1024) histC[i] = 0u;
  if (t < 16) sel[t] = 0u;
}

// ---------------- kernel A: positive histogram + static compact -----------
// Histograms x >= +0 (bins >= 2048). Candidates (x >= +4.0, ~28K) staged in
// per-block LDS, flushed with ONE global atomicAdd per block. Round-4 lesson:
// 28K per-lane same-address device atomics serialized at ~11 ns each (318us,
// all-idle counters); 2048 block-level atomics are ~free.
__global__ void __launch_bounds__(256) kA(const float4* __restrict__ cls, int n4,
                                          uint32_t* histC, uint32_t* sel,
                                          uint32_t* candKey, uint32_t* candIdx) {
  __shared__ uint32_t h[NBINS * 2];   // 32 KB, 2 interleaved copies
  __shared__ uint32_t lk[LCAP];       // local candidate keys
  __shared__ uint32_t li[LCAP];       // local candidate idxs
  __shared__ uint32_t lcnt, gbase;
  for (int i = threadIdx.x; i < NBINS * 2; i += 256) h[i] = 0u;
  if (threadIdx.x == 0) lcnt = 0u;
  __syncthreads();
  uint32_t sub = threadIdx.x & 1u;
  int stride = gridDim.x * blockDim.x;
  for (int i = blockIdx.x * blockDim.x + threadIdx.x; i < n4; i += stride) {
    float4 v = cls[i];
    uint32_t k4[4] = {fkey(v.x), fkey(v.y), fkey(v.z), fkey(v.w)};
#pragma unroll
    for (int c = 0; c < 4; ++c) {
      uint32_t k = k4[c];
      if (k & 0x80000000u) atomicAdd(&h[((k >> 20) << 1) | sub], 1u);
      if (k >= STATIC_KEY) {
        uint32_t p = atomicAdd(&lcnt, 1u);  // LDS atomic: cheap, distributed
        if (p < LCAP) { lk[p] = k; li[p] = (uint32_t)i * 4u + c; }
        else {  // spill (correctness-only path; ~never taken)
          uint32_t gp = atomicAdd(&sel[2], 1u);
          if (gp < CAP) { candKey[gp] = k; candIdx[gp] = (uint32_t)i * 4u + c; }
        }
      }
    }
  }
  __syncthreads();
  uint32_t c = lcnt; if (c > LCAP) c = LCAP;
  if (threadIdx.x == 0 && c) gbase = atomicAdd(&sel[2], c);  // ONE per block
  __syncthreads();
  for (uint32_t i = threadIdx.x; i < c; i += 256u) {
    uint32_t gp = gbase + i;
    if (gp < CAP) { candKey[gp] = lk[i]; candIdx[gp] = li[i]; }
  }
  for (int i = threadIdx.x; i < NBINS; i += 256) {
    uint32_t hc = h[i * 2] + h[i * 2 + 1];
    if (hc) atomicAdd(&histC[i], hc);
  }
}

// ---------------- kernel B: parallel suffix-scan bin pick -----------------
// sel[0]=bin, sel[1]=count above bin, sel[3]=needRescan (bin < STATIC_BIN).
__global__ void __launch_bounds__(1024) kB(const uint32_t* __restrict__ histC,
                                           uint32_t* sel) {
  __shared__ uint32_t s[1024];
  int t = threadIdx.x;
  uint32_t c0 = histC[t * 4 + 0], c1 = histC[t * 4 + 1];
  uint32_t c2 = histC[t * 4 + 2], c3 = histC[t * 4 + 3];
  s[t] = c0 + c1 + c2 + c3;
  __syncthreads();
  for (int off = 1; off < 1024; off <<= 1) {
    uint32_t add = (t + off < 1024) ? s[t + off] : 0u;
    __syncthreads();
    s[t] += add;
    __syncthreads();
  }
  uint32_t suff = s[t];
  uint32_t above = (t < 1023) ? s[t + 1] : 0u;
  bool crossing = (suff >= TARGET) && (t == 1023 || above < TARGET);
  if (crossing) {
    uint32_t cum = above;
    uint32_t cc[4] = {c0, c1, c2, c3};
    for (int j = 3; j >= 0; --j) {
      if (cum + cc[j] >= TARGET) {
        uint32_t bin = (uint32_t)(t * 4 + j);
        sel[0] = bin; sel[1] = cum;
        sel[3] = (bin < STATIC_BIN) ? 1u : 0u;
        break;
      }
      cum += cc[j];
    }
  }
  if (t == 512 && suff < TARGET) {  // degenerate: positives < TARGET
    sel[0] = 2048u; sel[1] = suff - c0; sel[3] = 1u;
  }
}

// ---------------- kernel E: fallback rescan (early-exit normally) ---------
// Only runs when the threshold bin fell below the static prefilter;
// appends the missing range {bin >= bsel, key < STATIC_KEY} to cand.
__global__ void kE(const float4* __restrict__ cls, int n4,
                   uint32_t* sel, uint32_t* candKey, uint32_t* candIdx) {
  if (sel[3] == 0u) return;  // static prefilter covered the threshold
  uint32_t bsel = sel[0];
  int stride = gridDim.x * blockDim.x;
  for (int i = blockIdx.x * blockDim.x + threadIdx.x; i < n4; i += stride) {
    float4 v = cls[i];
    uint32_t k4[4] = {fkey(v.x), fkey(v.y), fkey(v.z), fkey(v.w)};
#pragma unroll
    for (int c = 0; c < 4; ++c) {
      uint32_t k = k4[c];
      if ((k >> 20) >= bsel && k < STATIC_KEY) {
        uint32_t pos = atomicAdd(&sel[2], 1u);
        if (pos < CAP) { candKey[pos] = k; candIdx[pos] = (uint32_t)i * 4u + c; }
      }
    }
  }
}

// ---------------- kernel F1: refine threshold + select survivors ----------
// Single block: fine histogram -> threshold T; survivors (key >= T, ~1200)
// written to global srv as (p_bits<<32 | ~idx). Prefills outputs.
__global__ void __launch_bounds__(1024) kF1(
    const float* __restrict__ cls, const uint32_t* __restrict__ sel_ro,
    uint32_t* sel, const uint32_t* __restrict__ candKey,
    const uint32_t* __restrict__ candIdx,
    ull* __restrict__ srv, float* __restrict__ out, float* __restrict__ topScore) {
  __shared__ uint32_t fh[1024];
  __shared__ uint32_t TkeyS;
  int tid = threadIdx.x;
  uint32_t n = sel_ro[2]; if (n > CAP) n = CAP;
  uint32_t bsel = sel_ro[0], above = sel_ro[1];

  for (int i = tid; i < 1024; i += 1024) fh[i] = 0u;
  __syncthreads();
  for (uint32_t i = tid; i < n; i += 1024u) {
    uint32_t k = candKey[i];
    if ((k >> 20) == bsel) atomicAdd(&fh[(k >> 10) & 1023u], 1u);
  }
  __syncthreads();
  if (tid == 0) {
    uint32_t cum = above; int s = 1023;
    for (; s >= 0; --s) { cum += fh[s]; if (cum >= TARGET) break; }
    if (s < 0) s = 0;
    TkeyS = (bsel << 20) | ((uint32_t)s << 10);
  }
  __syncthreads();
  uint32_t T = TkeyS;

  for (uint32_t i = tid; i < n; i += 1024u) {
    uint32_t k = candKey[i];
    if (k >= T) {
      uint32_t pos = atomicAdd(&sel[4], 1u);
      if (pos < SRVCAP) {
        uint32_t idx = candIdx[i];
        float x = cls[idx];
        float p = 1.0f / (1.0f + expf(-x));  // np fp32 sigmoid
        srv[pos] = ((ull)__float_as_uint(p) << 32) | (ull)(uint32_t)(~idx);
      }
    }
  }
  // prefill (covers degenerate scount < 1000; cheap)
  for (int i = tid; i < 4000; i += 1024) out[i] = 0.0f;
  for (int i = tid; i < 1000; i += 1024) { out[5000 + i] = 0.0f; topScore[i] = 0.0f; }
}

// ---------------- kernel F2: rank survivors + emit ------------------------
// 32 blocks x 64: stage all survivor keys into LDS; thread i computes
// rank_i = #{j: skey_j > skey_i} (exact, keys unique) and emits row rank_i.
__global__ void __launch_bounds__(64) kF2(
    const float* __restrict__ box, const int* __restrict__ ph,
    const int* __restrict__ pw, const uint32_t* __restrict__ sel,
    const ull* __restrict__ srv, float* __restrict__ out,
    float* __restrict__ topScore, float* __restrict__ obox) {
  __shared__ __align__(16) ull sk[SRVCAP];
  int t = threadIdx.x;
  uint32_t scount = sel[4]; if (scount > SRVCAP) scount = SRVCAP;
  uint32_t pad = (scount + 1u) & ~1u;
  for (uint32_t i = t; i < pad; i += 64u) sk[i] = (i < scount) ? srv[i] : 0ull;
  __syncthreads();
  uint32_t i = blockIdx.x * 64u + (uint32_t)t;
  if (i >= scount) return;
  ull my = sk[i];
  uint32_t rank = 0;
#pragma unroll 4
  for (uint32_t j = 0; j < pad; j += 2u) {
    ull2 v = *reinterpret_cast<const ull2*>(&sk[j]);  // b128 broadcast read
    rank += (v.x > my) + (v.y > my);
  }
  if (rank >= TOPK) return;
  uint32_t idx = ~(uint32_t)my;
  float p = __uint_as_float((uint32_t)(my >> 32));
  uint32_t label = idx % NUM_CLASSES;
  uint32_t anchor = idx / NUM_CLASSES;
  float W = (float)pw[0], H = (float)ph[0];
  float b0 = box[anchor * 4u + 0u], b1 = box[anchor * 4u + 1u];
  float b2 = box[anchor * 4u + 2u], b3 = box[anchor * 4u + 3u];
  out[rank * 4 + 0] = fminf(fmaxf(b0 / W, 0.0f), 1.0f);
  out[rank * 4 + 1] = fminf(fmaxf(b1 / H, 0.0f), 1.0f);
  out[rank * 4 + 2] = fminf(fmaxf(b2 / W, 0.0f), 1.0f);
  out[rank * 4 + 3] = fminf(fmaxf(b3 / H, 0.0f), 1.0f);
  out[5000 + rank] = (float)label;
  topScore[rank] = p;
  float off = (float)label * MAX_COORD;  // class-aware NMS offset
  obox[rank * 4 + 0] = b0 + off; obox[rank * 4 + 1] = b1 + off;
  obox[rank * 4 + 2] = b2 + off; obox[rank * 4 + 3] = b3 + off;
}

// ---------------- kernel G: IoU suppression bitmasks (j > i) --------------
__global__ void kG(const float* __restrict__ obox, ull* __restrict__ masks) {
  int i = blockIdx.x;  // row 0..999
  float x1i = obox[i * 4 + 0], y1i = obox[i * 4 + 1];
  float x2i = obox[i * 4 + 2], y2i = obox[i * 4 + 3];
  float ai = (x2i - x1i) * (y2i - y1i);
  for (int base = 0; base < 1024; base += 256) {
    int jj = base + (int)threadIdx.x;
    bool bit = false;
    if (jj < TOPK && jj > i) {
      float x1j = obox[jj * 4 + 0], y1j = obox[jj * 4 + 1];
      float x2j = obox[jj * 4 + 2], y2j = obox[jj * 4 + 3];
      float aj = (x2j - x1j) * (y2j - y1j);
      float ix1 = fmaxf(x1i, x1j), iy1 = fmaxf(y1i, y1j);
      float ix2 = fminf(x2i, x2j), iy2 = fminf(y2i, y2j);
      float iw = fmaxf(ix2 - ix1, 0.0f), ih = fmaxf(iy2 - iy1, 0.0f);
      float inter = iw * ih;
      float iou = inter / (ai + aj - inter + 1e-9f);
      bit = iou > NMS_T;
    }
    ull m = __ballot(bit);
    if ((threadIdx.x & 63u) == 0u) masks[i * 16 + (jj >> 6)] = m;
  }
}

// ---------------- kernel H: LDS-staged single-wave greedy NMS -------------
__global__ void __launch_bounds__(256) kH(const float* __restrict__ topScore,
                                          const ull* __restrict__ masks,
                                          float* __restrict__ out) {
  __shared__ ull lmask[TOPK * 16];
  __shared__ uint32_t nzrow[TOPK];
  __shared__ ull keepsh[16];
  int t = threadIdx.x;
  for (int i = t; i < TOPK; i += 256) nzrow[i] = 0u;
  if (t < 16) keepsh[t] = 0ull;
  __syncthreads();
  for (int i = t; i < TOPK * 16; i += 256) {
    ull m = masks[i];
    lmask[i] = m;
    if (m) atomicOr(&nzrow[i >> 4], 1u);
  }
  for (int base = 0; base < 1024; base += 256) {
    int r = base + t;
    bool v = (r < TOPK) && (topScore[r] > CONF_T);
    ull b = __ballot(v);
    if ((t & 63) == 0) keepsh[(base >> 6) + (t >> 6)] = b;
  }
  __syncthreads();
  if (t < 64) {  // single-wave greedy loop, no barriers inside
    ull kw = (t < 16) ? keepsh[t] : 0ull;
    ull nzw = 0ull;
    if (t < 16) {
      for (int b = 0; b < 64; ++b) {
        int r = t * 64 + b;
        if (r < TOPK && nzrow[r]) nzw |= 1ull << b;
      }
    }
    for (int w = 0; w < 16; ++w) {
      ull cur = __shfl(kw, w) & __shfl(nzw, w);
      while (cur) {
        int b = __ffsll((long long)cur) - 1;
        int i = w * 64 + b;
        if (t < 16) kw &= ~lmask[i * 16 + t];  // row i suppresses only j > i
        ull nk = __shfl(kw, w);
        cur = nk & __shfl(nzw, w);
        cur &= (b == 63) ? 0ull : (~0ull << (b + 1));
      }
    }
    if (t < 16) keepsh[t] = kw;
  }
  __syncthreads();
  for (int r = t; r < TOPK; r += 256) {
    bool k = (keepsh[r >> 6] >> (r & 63)) & 1ull;
    float s = topScore[r];
    out[4000 + r] = k ? s : 0.0f;
    out[6000 + r] = k ? 1.0f : 0.0f;
  }
}

extern "C" void kernel_launch(void* const* d_in, const int* in_sizes, int n_in,
                              void* d_out, int out_size, void* d_ws, size_t ws_size,
                              hipStream_t stream) {
  const float* cls = (const float*)d_in[0];  // (1, N, 80) logits
  const float* box = (const float*)d_in[1];  // (1, N, 4)
  const int* ph = (const int*)d_in[2];       // img_h
  const int* pw = (const int*)d_in[3];       // img_w
  float* out = (float*)d_out;                // [boxes 4000 | scores 1000 | labels 1000 | keep 1000]
  int n = in_sizes[0];                       // 20,971,520 (divisible by 4)

  uint8_t* w = (uint8_t*)d_ws;
  uint32_t* histC   = (uint32_t*)(w);                               // 16 KB
  uint32_t* sel     = (uint32_t*)(w + 16384);                       // 64 B
  uint32_t* candKey = (uint32_t*)(w + 20480);                       // 192 KB
  uint32_t* candIdx = (uint32_t*)(w + 20480 + (size_t)CAP * 4);     // 192 KB
  ull*      srv     = (ull*)     (w + 20480 + (size_t)CAP * 8);     // 16 KB
  float*    topScore= (float*)   (w + 20480 + (size_t)CAP * 8 + 16384);         // 4 KB
  float*    obox    = (float*)   (w + 20480 + (size_t)CAP * 8 + 16384 + 4096);  // 16 KB
  ull*      masks   = (ull*)     (w + 20480 + (size_t)CAP * 8 + 16384 + 4096 + 16384); // 128 KB

  kz <<<1, 1024, 0, stream>>>(histC, sel);
  kA <<<2048, 256, 0, stream>>>((const float4*)cls, n / 4, histC, sel, candKey, candIdx);
  kB <<<1, 1024, 0, stream>>>(histC, sel);
  kE <<<2048, 256, 0, stream>>>((const float4*)cls, n / 4, sel, candKey, candIdx);
  kF1<<<1, 1024, 0, stream>>>(cls, sel, sel, candKey, candIdx, srv, out, topScore);
  kF2<<<SRVCAP / 64, 64, 0, stream>>>(box, ph, pw, sel, srv, out, topScore, obox);
  kG <<<TOPK, 256, 0, stream>>>(obox, masks);
  kH <<<1, 256, 0, stream>>>(topScore, masks, out);
}

// Round 6
// 235.529 us; speedup vs baseline: 2.2940x; 1.1770x over previous
//
#include <hip/hip_runtime.h>
#include <stdint.h>

#define NUM_CLASSES 80u
#define TOPK 1000
#define CONF_T 0.05f
#define NMS_T 0.6f
#define MAX_COORD 4096.0f
#define TARGET 1152u            // top-1000 + tie/superset slack
#define CAP 49152u              // candidate buffer capacity
#define SRVCAP 2048u            // survivor buffer (>= TARGET + boundary ties)
#define NBINS 4096              // coarse bins = key >> 20 (12 bits)
#define STATIC_KEY 0xC0800000u  // fkey(+4.0f): static candidate prefilter
#define STATIC_BIN 3080u        // STATIC_KEY >> 20
#define LCAP 512u               // per-block LDS candidate staging (kA)

typedef unsigned long long ull;
typedef ull ull2 __attribute__((ext_vector_type(2)));

// Monotone float->uint key: descending float == descending key
__device__ __forceinline__ uint32_t fkey(float x) {
  uint32_t k = __float_as_uint(x);
  return (k & 0x80000000u) ? ~k : (k | 0x80000000u);
}

// Inclusive suffix sum of per-thread v across 1024 threads (3 barriers).
// part = LDS[16]. Returns sum_{t' >= t} v[t']; part[0] ends as grand total.
__device__ __forceinline__ uint32_t suffix_scan_1024(uint32_t v, uint32_t* part,
                                                     int t) {
  int lane = t & 63, wid = t >> 6;
#pragma unroll
  for (int off = 1; off < 64; off <<= 1) {
    uint32_t x = __shfl_down(v, off);
    if (lane + off < 64) v += x;
  }
  if (lane == 0) part[wid] = v;  // lane 0 holds wave total
  __syncthreads();
  if (wid == 0) {
    uint32_t pv = (lane < 16) ? part[lane] : 0u;
#pragma unroll
    for (int off = 1; off < 16; off <<= 1) {
      uint32_t x = __shfl_down(pv, off);
      if (lane + off < 16) pv += x;
    }
    if (lane < 16) part[lane] = pv;  // inclusive suffix of wave totals
  }
  __syncthreads();
  uint32_t after = (wid < 15) ? part[wid + 1] : 0u;
  return v + after;
}

// ---------------- kernel Z: zero hist + counters (ws poisoned 0xAA) -------
__global__ void kz(uint32_t* histC, uint32_t* sel) {
  int t = threadIdx.x;
  for (int i = t; i < NBINS; i += 1024) histC[i] = 0u;
  if (t < 16) sel[t] = 0u;
}

// ---------------- kernel A: positive histogram + static compact -----------
// Histograms x >= +0 (bins >= 2048). Candidates (x >= +4.0, ~28K) staged in
// per-block LDS, flushed with ONE global atomicAdd per block (round-4 lesson:
// per-lane same-address device atomics serialize at ~11 ns each).
__global__ void __launch_bounds__(256) kA(const float4* __restrict__ cls, int n4,
                                          uint32_t* histC, uint32_t* sel,
                                          uint32_t* candKey, uint32_t* candIdx) {
  __shared__ uint32_t h[NBINS * 2];   // 32 KB, 2 interleaved copies
  __shared__ uint32_t lk[LCAP];       // local candidate keys
  __shared__ uint32_t li[LCAP];       // local candidate idxs
  __shared__ uint32_t lcnt, gbase;
  for (int i = threadIdx.x; i < NBINS * 2; i += 256) h[i] = 0u;
  if (threadIdx.x == 0) lcnt = 0u;
  __syncthreads();
  uint32_t sub = threadIdx.x & 1u;
  int stride = gridDim.x * blockDim.x;
  for (int i = blockIdx.x * blockDim.x + threadIdx.x; i < n4; i += stride) {
    float4 v = cls[i];
    uint32_t k4[4] = {fkey(v.x), fkey(v.y), fkey(v.z), fkey(v.w)};
#pragma unroll
    for (int c = 0; c < 4; ++c) {
      uint32_t k = k4[c];
      if (k & 0x80000000u) atomicAdd(&h[((k >> 20) << 1) | sub], 1u);
      if (k >= STATIC_KEY) {
        uint32_t p = atomicAdd(&lcnt, 1u);  // LDS atomic: cheap, distributed
        if (p < LCAP) { lk[p] = k; li[p] = (uint32_t)i * 4u + c; }
        else {  // spill (correctness-only path; ~never taken)
          uint32_t gp = atomicAdd(&sel[2], 1u);
          if (gp < CAP) { candKey[gp] = k; candIdx[gp] = (uint32_t)i * 4u + c; }
        }
      }
    }
  }
  __syncthreads();
  uint32_t c = lcnt; if (c > LCAP) c = LCAP;
  if (threadIdx.x == 0 && c) gbase = atomicAdd(&sel[2], c);  // ONE per block
  __syncthreads();
  for (uint32_t i = threadIdx.x; i < c; i += 256u) {
    uint32_t gp = gbase + i;
    if (gp < CAP) { candKey[gp] = lk[i]; candIdx[gp] = li[i]; }
  }
  for (int i = threadIdx.x; i < NBINS; i += 256) {
    uint32_t hc = h[i * 2] + h[i * 2 + 1];
    if (hc) atomicAdd(&histC[i], hc);
  }
}

// ---------------- kernel B: shfl-scan bin pick ----------------------------
// sel[0]=bin, sel[1]=count above bin, sel[3]=needRescan (bin < STATIC_BIN).
__global__ void __launch_bounds__(1024) kB(const uint32_t* __restrict__ histC,
                                           uint32_t* sel) {
  __shared__ uint32_t part[16];
  int t = threadIdx.x;
  uint32_t c0 = histC[t * 4 + 0], c1 = histC[t * 4 + 1];
  uint32_t c2 = histC[t * 4 + 2], c3 = histC[t * 4 + 3];
  uint32_t v = c0 + c1 + c2 + c3;
  uint32_t suff = suffix_scan_1024(v, part, t);
  uint32_t above = suff - v;  // suffix from bin 4t+4
  bool crossing = (suff >= TARGET) && (above < TARGET);
  if (crossing) {
    uint32_t cum = above;
    uint32_t cc[4] = {c0, c1, c2, c3};
    for (int j = 3; j >= 0; --j) {
      if (cum + cc[j] >= TARGET) {
        uint32_t bin = (uint32_t)(t * 4 + j);
        sel[0] = bin; sel[1] = cum;
        sel[3] = (bin < STATIC_BIN) ? 1u : 0u;
        break;
      }
      cum += cc[j];
    }
  }
  if (t == 512 && part[0] < TARGET) {  // degenerate: positives < TARGET
    sel[0] = 2048u; sel[1] = suff - c0; sel[3] = 1u;
  }
}

// ---------------- kernel E: fallback rescan (early-exit normally) ---------
__global__ void kE(const float4* __restrict__ cls, int n4,
                   uint32_t* sel, uint32_t* candKey, uint32_t* candIdx) {
  if (sel[3] == 0u) return;  // static prefilter covered the threshold
  uint32_t bsel = sel[0];
  int stride = gridDim.x * blockDim.x;
  for (int i = blockIdx.x * blockDim.x + threadIdx.x; i < n4; i += stride) {
    float4 v = cls[i];
    uint32_t k4[4] = {fkey(v.x), fkey(v.y), fkey(v.z), fkey(v.w)};
#pragma unroll
    for (int c = 0; c < 4; ++c) {
      uint32_t k = k4[c];
      if ((k >> 20) >= bsel && k < STATIC_KEY) {
        uint32_t pos = atomicAdd(&sel[2], 1u);
        if (pos < CAP) { candKey[pos] = k; candIdx[pos] = (uint32_t)i * 4u + c; }
      }
    }
  }
}

// ---------------- kernel F1: refine threshold + select survivors ----------
// Single block. Fine histogram -> parallel shfl suffix scan -> threshold T;
// survivors staged via LDS counter (NO device atomics — round-5 lesson:
// tid-0 serial 1024-bin walk + 1200 same-address device atomics cost 65 us).
__global__ void __launch_bounds__(1024) kF1(
    const float* __restrict__ cls, const uint32_t* __restrict__ sel_ro,
    uint32_t* sel, const uint32_t* __restrict__ candKey,
    const uint32_t* __restrict__ candIdx,
    ull* __restrict__ srv, float* __restrict__ out, float* __restrict__ topScore) {
  __shared__ uint32_t fh[1024];
  __shared__ uint32_t part[16];
  __shared__ uint32_t lidx[SRVCAP];
  __shared__ uint32_t scnt;
  __shared__ uint32_t TkeyS;
  int tid = threadIdx.x;
  uint32_t n = sel_ro[2]; if (n > CAP) n = CAP;
  uint32_t bsel = sel_ro[0], A = sel_ro[1];

  fh[tid] = 0u;
  if (tid == 0) scnt = 0u;
  __syncthreads();
  for (uint32_t i = tid; i < n; i += 1024u) {
    uint32_t k = candKey[i];
    if ((k >> 20) == bsel) atomicAdd(&fh[(k >> 10) & 1023u], 1u);
  }
  __syncthreads();
  uint32_t v = fh[tid];
  uint32_t suff = suffix_scan_1024(v, part, tid);
  uint32_t above = suff - v;
  if ((A + suff >= TARGET) && (A + above < TARGET))
    TkeyS = (bsel << 20) | ((uint32_t)tid << 10);   // unique crossing thread
  if (tid == 0 && A + suff < TARGET)                // degenerate: take all
    TkeyS = (bsel << 20);
  __syncthreads();
  uint32_t T = TkeyS;

  for (uint32_t i = tid; i < n; i += 1024u) {
    uint32_t k = candKey[i];
    if (k >= T) {
      uint32_t pos = atomicAdd(&scnt, 1u);          // LDS atomic only
      if (pos < SRVCAP) lidx[pos] = candIdx[i];
    }
  }
  __syncthreads();
  uint32_t c = scnt; if (c > SRVCAP) c = SRVCAP;
  if (tid == 0) sel[4] = c;                         // plain store, one block
  for (uint32_t i = tid; i < c; i += 1024u) {
    uint32_t idx = lidx[i];
    float x = cls[idx];
    float p = 1.0f / (1.0f + expf(-x));             // np fp32 sigmoid
    srv[i] = ((ull)__float_as_uint(p) << 32) | (ull)(uint32_t)(~idx);
  }
  // prefill (covers degenerate scount < 1000; cheap)
  for (int i = tid; i < 4000; i += 1024) out[i] = 0.0f;
  for (int i = tid; i < 1000; i += 1024) { out[5000 + i] = 0.0f; topScore[i] = 0.0f; }
}

// ---------------- kernel F2: rank survivors + emit ------------------------
// 32 blocks x 64: stage all survivor keys into LDS; thread i computes
// rank_i = #{j: skey_j > skey_i} (exact, keys unique) and emits row rank_i.
__global__ void __launch_bounds__(64) kF2(
    const float* __restrict__ box, const int* __restrict__ ph,
    const int* __restrict__ pw, const uint32_t* __restrict__ sel,
    const ull* __restrict__ srv, float* __restrict__ out,
    float* __restrict__ topScore, float* __restrict__ obox) {
  __shared__ __align__(16) ull sk[SRVCAP];
  int t = threadIdx.x;
  uint32_t scount = sel[4]; if (scount > SRVCAP) scount = SRVCAP;
  uint32_t pad = (scount + 1u) & ~1u;
  for (uint32_t i = t; i < pad; i += 64u) sk[i] = (i < scount) ? srv[i] : 0ull;
  __syncthreads();
  uint32_t i = blockIdx.x * 64u + (uint32_t)t;
  if (i >= scount) return;
  ull my = sk[i];
  uint32_t rank = 0;
#pragma unroll 4
  for (uint32_t j = 0; j < pad; j += 2u) {
    ull2 v = *reinterpret_cast<const ull2*>(&sk[j]);  // b128 broadcast read
    rank += (v.x > my) + (v.y > my);
  }
  if (rank >= TOPK) return;
  uint32_t idx = ~(uint32_t)my;
  float p = __uint_as_float((uint32_t)(my >> 32));
  uint32_t label = idx % NUM_CLASSES;
  uint32_t anchor = idx / NUM_CLASSES;
  float W = (float)pw[0], H = (float)ph[0];
  float b0 = box[anchor * 4u + 0u], b1 = box[anchor * 4u + 1u];
  float b2 = box[anchor * 4u + 2u], b3 = box[anchor * 4u + 3u];
  out[rank * 4 + 0] = fminf(fmaxf(b0 / W, 0.0f), 1.0f);
  out[rank * 4 + 1] = fminf(fmaxf(b1 / H, 0.0f), 1.0f);
  out[rank * 4 + 2] = fminf(fmaxf(b2 / W, 0.0f), 1.0f);
  out[rank * 4 + 3] = fminf(fmaxf(b3 / H, 0.0f), 1.0f);
  out[5000 + rank] = (float)label;
  topScore[rank] = p;
  float off = (float)label * MAX_COORD;  // class-aware NMS offset
  obox[rank * 4 + 0] = b0 + off; obox[rank * 4 + 1] = b1 + off;
  obox[rank * 4 + 2] = b2 + off; obox[rank * 4 + 3] = b3 + off;
}

// ---------------- kernel G: IoU suppression bitmasks (j > i) --------------
__global__ void kG(const float* __restrict__ obox, ull* __restrict__ masks) {
  int i = blockIdx.x;  // row 0..999
  float x1i = obox[i * 4 + 0], y1i = obox[i * 4 + 1];
  float x2i = obox[i * 4 + 2], y2i = obox[i * 4 + 3];
  float ai = (x2i - x1i) * (y2i - y1i);
  for (int base = 0; base < 1024; base += 256) {
    int jj = base + (int)threadIdx.x;
    bool bit = false;
    if (jj < TOPK && jj > i) {
      float x1j = obox[jj * 4 + 0], y1j = obox[jj * 4 + 1];
      float x2j = obox[jj * 4 + 2], y2j = obox[jj * 4 + 3];
      float aj = (x2j - x1j) * (y2j - y1j);
      float ix1 = fmaxf(x1i, x1j), iy1 = fmaxf(y1i, y1j);
      float ix2 = fminf(x2i, x2j), iy2 = fminf(y2i, y2j);
      float iw = fmaxf(ix2 - ix1, 0.0f), ih = fmaxf(iy2 - iy1, 0.0f);
      float inter = iw * ih;
      float iou = inter / (ai + aj - inter + 1e-9f);
      bit = iou > NMS_T;
    }
    ull m = __ballot(bit);
    if ((threadIdx.x & 63u) == 0u) masks[i * 16 + (jj >> 6)] = m;
  }
}

// ---------------- kernel H: LDS-staged single-wave greedy NMS -------------
__global__ void __launch_bounds__(256) kH(const float* __restrict__ topScore,
                                          const ull* __restrict__ masks,
                                          float* __restrict__ out) {
  __shared__ ull lmask[TOPK * 16];
  __shared__ uint32_t nzrow[TOPK];
  __shared__ ull keepsh[16];
  int t = threadIdx.x;
  for (int i = t; i < TOPK; i += 256) nzrow[i] = 0u;
  if (t < 16) keepsh[t] = 0ull;
  __syncthreads();
  for (int i = t; i < TOPK * 16; i += 256) {
    ull m = masks[i];
    lmask[i] = m;
    if (m) atomicOr(&nzrow[i >> 4], 1u);
  }
  for (int base = 0; base < 1024; base += 256) {
    int r = base + t;
    bool v = (r < TOPK) && (topScore[r] > CONF_T);
    ull b = __ballot(v);
    if ((t & 63) == 0) keepsh[(base >> 6) + (t >> 6)] = b;
  }
  __syncthreads();
  if (t < 64) {  // single-wave greedy loop, no barriers inside
    ull kw = (t < 16) ? keepsh[t] : 0ull;
    ull nzw = 0ull;
    if (t < 16) {
      for (int b = 0; b < 64; ++b) {
        int r = t * 64 + b;
        if (r < TOPK && nzrow[r]) nzw |= 1ull << b;
      }
    }
    for (int w = 0; w < 16; ++w) {
      ull cur = __shfl(kw, w) & __shfl(nzw, w);
      while (cur) {
        int b = __ffsll((long long)cur) - 1;
        int i = w * 64 + b;
        if (t < 16) kw &= ~lmask[i * 16 + t];  // row i suppresses only j > i
        ull nk = __shfl(kw, w);
        cur = nk & __shfl(nzw, w);
        cur &= (b == 63) ? 0ull : (~0ull << (b + 1));
      }
    }
    if (t < 16) keepsh[t] = kw;
  }
  __syncthreads();
  for (int r = t; r < TOPK; r += 256) {
    bool k = (keepsh[r >> 6] >> (r & 63)) & 1ull;
    float s = topScore[r];
    out[4000 + r] = k ? s : 0.0f;
    out[6000 + r] = k ? 1.0f : 0.0f;
  }
}

extern "C" void kernel_launch(void* const* d_in, const int* in_sizes, int n_in,
                              void* d_out, int out_size, void* d_ws, size_t ws_size,
                              hipStream_t stream) {
  const float* cls = (const float*)d_in[0];  // (1, N, 80) logits
  const float* box = (const float*)d_in[1];  // (1, N, 4)
  const int* ph = (const int*)d_in[2];       // img_h
  const int* pw = (const int*)d_in[3];       // img_w
  float* out = (float*)d_out;                // [boxes 4000 | scores 1000 | labels 1000 | keep 1000]
  int n = in_sizes[0];                       // 20,971,520 (divisible by 4)

  uint8_t* w = (uint8_t*)d_ws;
  uint32_t* histC   = (uint32_t*)(w);                               // 16 KB
  uint32_t* sel     = (uint32_t*)(w + 16384);                       // 64 B
  uint32_t* candKey = (uint32_t*)(w + 20480);                       // 192 KB
  uint32_t* candIdx = (uint32_t*)(w + 20480 + (size_t)CAP * 4);     // 192 KB
  ull*      srv     = (ull*)     (w + 20480 + (size_t)CAP * 8);     // 16 KB
  float*    topScore= (float*)   (w + 20480 + (size_t)CAP * 8 + 16384);         // 4 KB
  float*    obox    = (float*)   (w + 20480 + (size_t)CAP * 8 + 16384 + 4096);  // 16 KB
  ull*      masks   = (ull*)     (w + 20480 + (size_t)CAP * 8 + 16384 + 4096 + 16384); // 128 KB

  kz <<<1, 1024, 0, stream>>>(histC, sel);
  kA <<<2048, 256, 0, stream>>>((const float4*)cls, n / 4, histC, sel, candKey, candIdx);
  kB <<<1, 1024, 0, stream>>>(histC, sel);
  kE <<<2048, 256, 0, stream>>>((const float4*)cls, n / 4, sel, candKey, candIdx);
  kF1<<<1, 1024, 0, stream>>>(cls, sel, sel, candKey, candIdx, srv, out, topScore);
  kF2<<<SRVCAP / 64, 64, 0, stream>>>(box, ph, pw, sel, srv, out, topScore, obox);
  kG <<<TOPK, 256, 0, stream>>>(obox, masks);
  kH <<<1, 256, 0, stream>>>(topScore, masks, out);
}